// Round 1
// baseline (365.969 us; speedup 1.0000x reference)
//
#include <hip/hip_runtime.h>
#include <hip/hip_bf16.h>

// GCN 2-layer: h = relu(Agg(x@W1)+b1); out = relu(Agg(h@W2)+b2)
// Agg uses symmetric normalization with self-loops (PyG GCNConv default).
// Strategy: build CSR (by dst) on device each call, then per-node gather-reduce.

// ---------------- setup kernels ----------------

__global__ void count_k(const int* __restrict__ dst, int* __restrict__ counts, int E) {
    int e = blockIdx.x * 256 + threadIdx.x;
    if (e < E) atomicAdd(&counts[dst[e]], 1);
}

__global__ void dinv_k(const int* __restrict__ counts, float* __restrict__ dinv, int n) {
    int i = blockIdx.x * 256 + threadIdx.x;
    if (i < n) {
        float deg = (float)(counts[i] + 1);   // +1 self-loop
        dinv[i] = rsqrtf(deg);
    }
}

// single-block exclusive scan over counts -> offs (and cursor copy)
__global__ __launch_bounds__(1024) void scan_k(const int* __restrict__ counts,
                                               int* __restrict__ offs,
                                               int* __restrict__ cursor, int n) {
    __shared__ int sh[1024];
    __shared__ int carry_sh;
    int tid = threadIdx.x;
    if (tid == 0) carry_sh = 0;
    __syncthreads();
    for (int base = 0; base < n; base += 1024) {
        int i = base + tid;
        int v = (i < n) ? counts[i] : 0;
        sh[tid] = v;
        __syncthreads();
        for (int off = 1; off < 1024; off <<= 1) {
            int t = (tid >= off) ? sh[tid - off] : 0;
            __syncthreads();
            sh[tid] += t;
            __syncthreads();
        }
        int carry = carry_sh;
        int excl = carry + sh[tid] - v;
        if (i < n) { offs[i] = excl; cursor[i] = excl; }
        __syncthreads();                 // all reads of carry_sh done
        if (tid == 0) carry_sh = carry + sh[1023];
        __syncthreads();
    }
    if (tid == 0) offs[n] = carry_sh;
}

__global__ void fill_k(const int* __restrict__ src, const int* __restrict__ dst,
                       const float* __restrict__ dinv, int* __restrict__ cursor,
                       int* __restrict__ adj_src, float* __restrict__ adj_w, int E) {
    int e = blockIdx.x * 256 + threadIdx.x;
    if (e < E) {
        int s = src[e], d = dst[e];
        int p = atomicAdd(&cursor[d], 1);
        adj_src[p] = s;
        adj_w[p] = dinv[s] * dinv[d];
    }
}

// ---------------- GEMM: H[n][128] = X[n][128] @ W[128][128] ----------------
// block: 256 threads, 32 rows per block. Thread (rg,cg) computes a 4x4 tile.

__global__ __launch_bounds__(256) void gemm128(const float* __restrict__ X,
                                               const float* __restrict__ W,
                                               float* __restrict__ H, int n) {
    __shared__ __align__(16) float xs[32][128];
    int base = blockIdx.x * 32;
    int tid = threadIdx.x;
    int rows_here = n - base; if (rows_here > 32) rows_here = 32;

    const float4* X4 = (const float4*)(X + (size_t)base * 128);
    float4* xs4 = (float4*)xs;
#pragma unroll
    for (int u = 0; u < 4; ++u) {
        int idx = u * 256 + tid;          // float4 index; 32 float4 per row
        int r = idx >> 5;
        float4 v = make_float4(0.f, 0.f, 0.f, 0.f);
        if (r < rows_here) v = X4[idx];
        xs4[idx] = v;
    }
    __syncthreads();

    int cg = tid & 31;   // cols cg*4 .. cg*4+3
    int rg = tid >> 5;   // rows rg*4 .. rg*4+3
    float acc[4][4] = {};

    for (int k0 = 0; k0 < 128; k0 += 4) {
        float4 a[4];
#pragma unroll
        for (int j = 0; j < 4; ++j)
            a[j] = *(const float4*)&xs[rg * 4 + j][k0];
#pragma unroll
        for (int kk = 0; kk < 4; ++kk) {
            float4 w = *(const float4*)&W[(size_t)(k0 + kk) * 128 + cg * 4];
#pragma unroll
            for (int j = 0; j < 4; ++j) {
                float av = ((const float*)&a[j])[kk];
                acc[j][0] = fmaf(av, w.x, acc[j][0]);
                acc[j][1] = fmaf(av, w.y, acc[j][1]);
                acc[j][2] = fmaf(av, w.z, acc[j][2]);
                acc[j][3] = fmaf(av, w.w, acc[j][3]);
            }
        }
    }

#pragma unroll
    for (int j = 0; j < 4; ++j) {
        int row = base + rg * 4 + j;
        if (row < n) {
            float4 v = make_float4(acc[j][0], acc[j][1], acc[j][2], acc[j][3]);
            *(float4*)&H[(size_t)row * 128 + cg * 4] = v;
        }
    }
}

// ---------------- aggregation: one wave per node, lane = 2 features ----------------

__global__ __launch_bounds__(256) void agg_k(const float* __restrict__ H,
                                             const int* __restrict__ offs,
                                             const int* __restrict__ adj_src,
                                             const float* __restrict__ adj_w,
                                             const float* __restrict__ dinv,
                                             const float* __restrict__ bias,
                                             float* __restrict__ out, int n) {
    int node = blockIdx.x * 4 + (threadIdx.x >> 6);
    if (node >= n) return;
    int lane = threadIdx.x & 63;

    const float2* H2 = (const float2*)H;
    float di = dinv[node];
    float sn = di * di;                       // self-loop norm
    float2 self = H2[(size_t)node * 64 + lane];
    float2 acc;
    acc.x = self.x * sn;
    acc.y = self.y * sn;

    int e1 = offs[node + 1];
    for (int e = offs[node]; e < e1; ++e) {
        int s = adj_src[e];
        float w = adj_w[e];
        float2 hv = H2[(size_t)s * 64 + lane];
        acc.x = fmaf(hv.x, w, acc.x);
        acc.y = fmaf(hv.y, w, acc.y);
    }
    float2 b = ((const float2*)bias)[lane];
    acc.x = fmaxf(acc.x + b.x, 0.f);
    acc.y = fmaxf(acc.y + b.y, 0.f);
    ((float2*)out)[(size_t)node * 64 + lane] = acc;
}

// ---------------- launch ----------------

extern "C" void kernel_launch(void* const* d_in, const int* in_sizes, int n_in,
                              void* d_out, int out_size, void* d_ws, size_t ws_size,
                              hipStream_t stream) {
    const float* x  = (const float*)d_in[0];
    const int*   ei = (const int*)d_in[1];
    const float* W1 = (const float*)d_in[2];
    const float* b1 = (const float*)d_in[3];
    const float* W2 = (const float*)d_in[4];
    const float* b2 = (const float*)d_in[5];
    float* out = (float*)d_out;

    const int N = in_sizes[0] / 128;
    const int E = in_sizes[1] / 2;
    const int* src = ei;
    const int* dst = ei + E;

    // workspace carve-up (256B aligned)
    char* ws = (char*)d_ws;
    size_t off = 0;
    auto alloc = [&](size_t bytes) -> void* {
        void* p = ws + off;
        off = (off + bytes + 255) & ~(size_t)255;
        return p;
    };
    int*   counts  = (int*)  alloc((size_t)N * 4);
    int*   offs    = (int*)  alloc((size_t)(N + 1) * 4);
    int*   cursor  = (int*)  alloc((size_t)N * 4);
    float* dinv    = (float*)alloc((size_t)N * 4);
    int*   adj_src = (int*)  alloc((size_t)E * 4);
    float* adj_w   = (float*)alloc((size_t)E * 4);
    float* h       = (float*)alloc((size_t)N * 128 * 4);
    float* t       = (float*)alloc((size_t)N * 128 * 4);
    (void)ws_size; (void)n_in; (void)out_size;

    int gE = (E + 255) / 256;
    int gN = (N + 255) / 256;
    int gG = (N + 31) / 32;
    int gA = (N + 3) / 4;

    hipMemsetAsync(counts, 0, (size_t)N * 4, stream);
    count_k<<<gE, 256, 0, stream>>>(dst, counts, E);
    dinv_k<<<gN, 256, 0, stream>>>(counts, dinv, N);
    scan_k<<<1, 1024, 0, stream>>>(counts, offs, cursor, N);
    fill_k<<<gE, 256, 0, stream>>>(src, dst, dinv, cursor, adj_src, adj_w, E);

    gemm128<<<gG, 256, 0, stream>>>(x, W1, h, N);
    agg_k<<<gA, 256, 0, stream>>>(h, offs, adj_src, adj_w, dinv, b1, t, N);
    gemm128<<<gG, 256, 0, stream>>>(t, W2, h, N);
    agg_k<<<gA, 256, 0, stream>>>(h, offs, adj_src, adj_w, dinv, b2, out, N);
}

// Round 2
// 285.704 us; speedup vs baseline: 1.2809x; 1.2809x over previous
//
#include <hip/hip_runtime.h>
#include <hip/hip_bf16.h>

// GCN 2-layer: h = relu(Agg(x@W1)+b1); out = relu(Agg(h@W2)+b2)
// Agg uses symmetric normalization with self-loops (PyG GCNConv default).
// Strategy: build CSR (by dst) on device each call, then per-node gather-reduce.
// R1: two-level parallel scan (single-block scan_k was 92us = 25% of runtime).

// ---------------- setup kernels ----------------

__global__ void count_k(const int* __restrict__ dst, int* __restrict__ counts, int E) {
    int e = blockIdx.x * 256 + threadIdx.x;
    if (e < E) atomicAdd(&counts[dst[e]], 1);
}

__global__ void dinv_k(const int* __restrict__ counts, float* __restrict__ dinv, int n) {
    int i = blockIdx.x * 256 + threadIdx.x;
    if (i < n) {
        float deg = (float)(counts[i] + 1);   // +1 self-loop
        dinv[i] = rsqrtf(deg);
    }
}

// ---- two-level exclusive scan over counts[n] -> offs[n+1], cursor[n] ----
// level A: each 256-thread block reduces 1024 counts -> blockSums[b]

__global__ __launch_bounds__(256) void scanA_k(const int* __restrict__ counts,
                                               int* __restrict__ blockSums, int n) {
    __shared__ int sh[256];
    int base = blockIdx.x * 1024;
    int tid = threadIdx.x;
    int s = 0;
#pragma unroll
    for (int u = 0; u < 4; ++u) {
        int i = base + u * 256 + tid;
        if (i < n) s += counts[i];
    }
    sh[tid] = s;
    __syncthreads();
    for (int off = 128; off > 0; off >>= 1) {
        if (tid < off) sh[tid] += sh[tid + off];
        __syncthreads();
    }
    if (tid == 0) blockSums[blockIdx.x] = sh[0];
}

// level B: exclusive-scan blockSums[nb] in place (nb <= 1024), total -> offs[n]

__global__ __launch_bounds__(256) void scanB_k(int* __restrict__ blockSums, int nb,
                                               int* __restrict__ offs, int n) {
    __shared__ int sh[1024];
    int tid = threadIdx.x;
    for (int i = tid; i < nb; i += 256) sh[i] = blockSums[i];
    __syncthreads();
    if (tid == 0) {
        int run = 0;
        for (int i = 0; i < nb; ++i) { int v = sh[i]; sh[i] = run; run += v; }
        offs[n] = run;
    }
    __syncthreads();
    for (int i = tid; i < nb; i += 256) blockSums[i] = sh[i];
}

// level C: per-block exclusive scan (+block offset) -> offs, cursor

__global__ __launch_bounds__(256) void scanC_k(const int* __restrict__ counts,
                                               const int* __restrict__ blockSums,
                                               int* __restrict__ offs,
                                               int* __restrict__ cursor, int n) {
    __shared__ int sh[256];
    int base = blockIdx.x * 1024;
    int tid = threadIdx.x;
    int v[4];
    int s = 0;
#pragma unroll
    for (int u = 0; u < 4; ++u) {
        int i = base + tid * 4 + u;
        v[u] = (i < n) ? counts[i] : 0;
        s += v[u];
    }
    sh[tid] = s;
    __syncthreads();
    for (int off = 1; off < 256; off <<= 1) {
        int t = (tid >= off) ? sh[tid - off] : 0;
        __syncthreads();
        sh[tid] += t;
        __syncthreads();
    }
    int excl = blockSums[blockIdx.x] + sh[tid] - s;
#pragma unroll
    for (int u = 0; u < 4; ++u) {
        int i = base + tid * 4 + u;
        if (i < n) { offs[i] = excl; cursor[i] = excl; }
        excl += v[u];
    }
}

__global__ void fill_k(const int* __restrict__ src, const int* __restrict__ dst,
                       const float* __restrict__ dinv, int* __restrict__ cursor,
                       int* __restrict__ adj_src, float* __restrict__ adj_w, int E) {
    int e = blockIdx.x * 256 + threadIdx.x;
    if (e < E) {
        int s = src[e], d = dst[e];
        int p = atomicAdd(&cursor[d], 1);
        adj_src[p] = s;
        adj_w[p] = dinv[s] * dinv[d];
    }
}

// ---------------- GEMM: H[n][128] = X[n][128] @ W[128][128] ----------------
// block: 256 threads, 32 rows per block. Thread (rg,cg) computes a 4x4 tile.

__global__ __launch_bounds__(256) void gemm128(const float* __restrict__ X,
                                               const float* __restrict__ W,
                                               float* __restrict__ H, int n) {
    __shared__ __align__(16) float xs[32][128];
    int base = blockIdx.x * 32;
    int tid = threadIdx.x;
    int rows_here = n - base; if (rows_here > 32) rows_here = 32;

    const float4* X4 = (const float4*)(X + (size_t)base * 128);
    float4* xs4 = (float4*)xs;
#pragma unroll
    for (int u = 0; u < 4; ++u) {
        int idx = u * 256 + tid;          // float4 index; 32 float4 per row
        int r = idx >> 5;
        float4 v = make_float4(0.f, 0.f, 0.f, 0.f);
        if (r < rows_here) v = X4[idx];
        xs4[idx] = v;
    }
    __syncthreads();

    int cg = tid & 31;   // cols cg*4 .. cg*4+3
    int rg = tid >> 5;   // rows rg*4 .. rg*4+3
    float acc[4][4] = {};

    for (int k0 = 0; k0 < 128; k0 += 4) {
        float4 a[4];
#pragma unroll
        for (int j = 0; j < 4; ++j)
            a[j] = *(const float4*)&xs[rg * 4 + j][k0];
#pragma unroll
        for (int kk = 0; kk < 4; ++kk) {
            float4 w = *(const float4*)&W[(size_t)(k0 + kk) * 128 + cg * 4];
#pragma unroll
            for (int j = 0; j < 4; ++j) {
                float av = ((const float*)&a[j])[kk];
                acc[j][0] = fmaf(av, w.x, acc[j][0]);
                acc[j][1] = fmaf(av, w.y, acc[j][1]);
                acc[j][2] = fmaf(av, w.z, acc[j][2]);
                acc[j][3] = fmaf(av, w.w, acc[j][3]);
            }
        }
    }

#pragma unroll
    for (int j = 0; j < 4; ++j) {
        int row = base + rg * 4 + j;
        if (row < n) {
            float4 v = make_float4(acc[j][0], acc[j][1], acc[j][2], acc[j][3]);
            *(float4*)&H[(size_t)row * 128 + cg * 4] = v;
        }
    }
}

// ---------------- aggregation: one wave per node, lane = 2 features ----------------

__global__ __launch_bounds__(256) void agg_k(const float* __restrict__ H,
                                             const int* __restrict__ offs,
                                             const int* __restrict__ adj_src,
                                             const float* __restrict__ adj_w,
                                             const float* __restrict__ dinv,
                                             const float* __restrict__ bias,
                                             float* __restrict__ out, int n) {
    int node = blockIdx.x * 4 + (threadIdx.x >> 6);
    if (node >= n) return;
    int lane = threadIdx.x & 63;

    const float2* H2 = (const float2*)H;
    float di = dinv[node];
    float sn = di * di;                       // self-loop norm
    float2 self = H2[(size_t)node * 64 + lane];
    float2 acc;
    acc.x = self.x * sn;
    acc.y = self.y * sn;

    int e1 = offs[node + 1];
    for (int e = offs[node]; e < e1; ++e) {
        int s = adj_src[e];
        float w = adj_w[e];
        float2 hv = H2[(size_t)s * 64 + lane];
        acc.x = fmaf(hv.x, w, acc.x);
        acc.y = fmaf(hv.y, w, acc.y);
    }
    float2 b = ((const float2*)bias)[lane];
    acc.x = fmaxf(acc.x + b.x, 0.f);
    acc.y = fmaxf(acc.y + b.y, 0.f);
    ((float2*)out)[(size_t)node * 64 + lane] = acc;
}

// ---------------- launch ----------------

extern "C" void kernel_launch(void* const* d_in, const int* in_sizes, int n_in,
                              void* d_out, int out_size, void* d_ws, size_t ws_size,
                              hipStream_t stream) {
    const float* x  = (const float*)d_in[0];
    const int*   ei = (const int*)d_in[1];
    const float* W1 = (const float*)d_in[2];
    const float* b1 = (const float*)d_in[3];
    const float* W2 = (const float*)d_in[4];
    const float* b2 = (const float*)d_in[5];
    float* out = (float*)d_out;

    const int N = in_sizes[0] / 128;
    const int E = in_sizes[1] / 2;
    const int* src = ei;
    const int* dst = ei + E;

    // workspace carve-up (256B aligned)
    char* ws = (char*)d_ws;
    size_t off = 0;
    auto alloc = [&](size_t bytes) -> void* {
        void* p = ws + off;
        off = (off + bytes + 255) & ~(size_t)255;
        return p;
    };
    int*   counts  = (int*)  alloc((size_t)N * 4);
    int*   offs    = (int*)  alloc((size_t)(N + 1) * 4);
    int*   cursor  = (int*)  alloc((size_t)N * 4);
    float* dinv    = (float*)alloc((size_t)N * 4);
    int*   adj_src = (int*)  alloc((size_t)E * 4);
    float* adj_w   = (float*)alloc((size_t)E * 4);
    float* h       = (float*)alloc((size_t)N * 128 * 4);
    float* t       = (float*)alloc((size_t)N * 128 * 4);
    int*   blockSums = (int*)alloc((size_t)1024 * 4);
    (void)ws_size; (void)n_in; (void)out_size;

    int gE = (E + 255) / 256;
    int gN = (N + 255) / 256;
    int gG = (N + 31) / 32;
    int gA = (N + 3) / 4;
    int nb = (N + 1023) / 1024;          // scan blocks (<=1024 supported)

    hipMemsetAsync(counts, 0, (size_t)N * 4, stream);
    count_k<<<gE, 256, 0, stream>>>(dst, counts, E);
    dinv_k<<<gN, 256, 0, stream>>>(counts, dinv, N);
    scanA_k<<<nb, 256, 0, stream>>>(counts, blockSums, N);
    scanB_k<<<1, 256, 0, stream>>>(blockSums, nb, offs, N);
    scanC_k<<<nb, 256, 0, stream>>>(counts, blockSums, offs, cursor, N);
    fill_k<<<gE, 256, 0, stream>>>(src, dst, dinv, cursor, adj_src, adj_w, E);

    gemm128<<<gG, 256, 0, stream>>>(x, W1, h, N);
    agg_k<<<gA, 256, 0, stream>>>(h, offs, adj_src, adj_w, dinv, b1, t, N);
    gemm128<<<gG, 256, 0, stream>>>(t, W2, h, N);
    agg_k<<<gA, 256, 0, stream>>>(h, offs, adj_src, adj_w, dinv, b2, out, N);
}

// Round 3
// 241.627 us; speedup vs baseline: 1.5146x; 1.1824x over previous
//
#include <hip/hip_runtime.h>
#include <hip/hip_bf16.h>

// GCN 2-layer: h = relu(Agg(x@W1)+b1); out = relu(Agg(h@W2)+b2)
// R1: two-level parallel scan.
// R2: agg gather loop unrolled x8 (latency-bound -> 8 outstanding gathers);
//     symmetric norm folded into gemm epilogue (h2 = (X@W)*dinv[row]) so the
//     per-edge weight load and adj_w array disappear.

// ---------------- setup kernels ----------------

__global__ void count_k(const int* __restrict__ dst, int* __restrict__ counts, int E) {
    int e = blockIdx.x * 256 + threadIdx.x;
    if (e < E) atomicAdd(&counts[dst[e]], 1);
}

__global__ void dinv_k(const int* __restrict__ counts, float* __restrict__ dinv, int n) {
    int i = blockIdx.x * 256 + threadIdx.x;
    if (i < n) {
        float deg = (float)(counts[i] + 1);   // +1 self-loop
        dinv[i] = rsqrtf(deg);
    }
}

// ---- two-level exclusive scan over counts[n] -> offs[n+1], cursor[n] ----

__global__ __launch_bounds__(256) void scanA_k(const int* __restrict__ counts,
                                               int* __restrict__ blockSums, int n) {
    __shared__ int sh[256];
    int base = blockIdx.x * 1024;
    int tid = threadIdx.x;
    int s = 0;
#pragma unroll
    for (int u = 0; u < 4; ++u) {
        int i = base + u * 256 + tid;
        if (i < n) s += counts[i];
    }
    sh[tid] = s;
    __syncthreads();
    for (int off = 128; off > 0; off >>= 1) {
        if (tid < off) sh[tid] += sh[tid + off];
        __syncthreads();
    }
    if (tid == 0) blockSums[blockIdx.x] = sh[0];
}

__global__ __launch_bounds__(256) void scanB_k(int* __restrict__ blockSums, int nb,
                                               int* __restrict__ offs, int n) {
    __shared__ int sh[1024];
    int tid = threadIdx.x;
    for (int i = tid; i < nb; i += 256) sh[i] = blockSums[i];
    __syncthreads();
    if (tid == 0) {
        int run = 0;
        for (int i = 0; i < nb; ++i) { int v = sh[i]; sh[i] = run; run += v; }
        offs[n] = run;
    }
    __syncthreads();
    for (int i = tid; i < nb; i += 256) blockSums[i] = sh[i];
}

__global__ __launch_bounds__(256) void scanC_k(const int* __restrict__ counts,
                                               const int* __restrict__ blockSums,
                                               int* __restrict__ offs,
                                               int* __restrict__ cursor, int n) {
    __shared__ int sh[256];
    int base = blockIdx.x * 1024;
    int tid = threadIdx.x;
    int v[4];
    int s = 0;
#pragma unroll
    for (int u = 0; u < 4; ++u) {
        int i = base + tid * 4 + u;
        v[u] = (i < n) ? counts[i] : 0;
        s += v[u];
    }
    sh[tid] = s;
    __syncthreads();
    for (int off = 1; off < 256; off <<= 1) {
        int t = (tid >= off) ? sh[tid - off] : 0;
        __syncthreads();
        sh[tid] += t;
        __syncthreads();
    }
    int excl = blockSums[blockIdx.x] + sh[tid] - s;
#pragma unroll
    for (int u = 0; u < 4; ++u) {
        int i = base + tid * 4 + u;
        if (i < n) { offs[i] = excl; cursor[i] = excl; }
        excl += v[u];
    }
}

__global__ void fill_k(const int* __restrict__ src, const int* __restrict__ dst,
                       int* __restrict__ cursor, int* __restrict__ adj_src, int E) {
    int e = blockIdx.x * 256 + threadIdx.x;
    if (e < E) {
        int d = dst[e];
        int p = atomicAdd(&cursor[d], 1);
        adj_src[p] = src[e];
    }
}

// ---------------- GEMM: H2[n][128] = (X[n][128] @ W[128][128]) * dinv[row] ----------------

__global__ __launch_bounds__(256) void gemm128s(const float* __restrict__ X,
                                                const float* __restrict__ W,
                                                const float* __restrict__ dinv,
                                                float* __restrict__ H, int n) {
    __shared__ __align__(16) float xs[32][128];
    int base = blockIdx.x * 32;
    int tid = threadIdx.x;
    int rows_here = n - base; if (rows_here > 32) rows_here = 32;

    const float4* X4 = (const float4*)(X + (size_t)base * 128);
    float4* xs4 = (float4*)xs;
#pragma unroll
    for (int u = 0; u < 4; ++u) {
        int idx = u * 256 + tid;          // float4 index; 32 float4 per row
        int r = idx >> 5;
        float4 v = make_float4(0.f, 0.f, 0.f, 0.f);
        if (r < rows_here) v = X4[idx];
        xs4[idx] = v;
    }
    __syncthreads();

    int cg = tid & 31;   // cols cg*4 .. cg*4+3
    int rg = tid >> 5;   // rows rg*4 .. rg*4+3
    float acc[4][4] = {};

    for (int k0 = 0; k0 < 128; k0 += 4) {
        float4 a[4];
#pragma unroll
        for (int j = 0; j < 4; ++j)
            a[j] = *(const float4*)&xs[rg * 4 + j][k0];
#pragma unroll
        for (int kk = 0; kk < 4; ++kk) {
            float4 w = *(const float4*)&W[(size_t)(k0 + kk) * 128 + cg * 4];
#pragma unroll
            for (int j = 0; j < 4; ++j) {
                float av = ((const float*)&a[j])[kk];
                acc[j][0] = fmaf(av, w.x, acc[j][0]);
                acc[j][1] = fmaf(av, w.y, acc[j][1]);
                acc[j][2] = fmaf(av, w.z, acc[j][2]);
                acc[j][3] = fmaf(av, w.w, acc[j][3]);
            }
        }
    }

#pragma unroll
    for (int j = 0; j < 4; ++j) {
        int row = base + rg * 4 + j;
        if (row < n) {
            float sc = dinv[row];
            float4 v = make_float4(acc[j][0] * sc, acc[j][1] * sc,
                                   acc[j][2] * sc, acc[j][3] * sc);
            *(float4*)&H[(size_t)row * 128 + cg * 4] = v;
        }
    }
}

// ---------------- aggregation ----------------
// H2 is pre-scaled by dinv[src]. out[d] = relu(dinv[d]*(sum h2[s] + h2[d]) + b)
// One wave per node, lane = 2 features, edge loop unrolled x8 for MLP.

__global__ __launch_bounds__(256) void agg_k(const float* __restrict__ Hs,
                                             const int* __restrict__ offs,
                                             const int* __restrict__ adj_src,
                                             const float* __restrict__ dinv,
                                             const float* __restrict__ bias,
                                             float* __restrict__ out, int n) {
    int node = blockIdx.x * 4 + (threadIdx.x >> 6);
    if (node >= n) return;
    int lane = threadIdx.x & 63;

    const float2* H2 = (const float2*)Hs;
    float2 acc = H2[(size_t)node * 64 + lane];     // self term (pre-scaled)

    int e = offs[node];
    int e1 = offs[node + 1];

    for (; e + 8 <= e1; e += 8) {
        int s[8];
#pragma unroll
        for (int i = 0; i < 8; ++i) s[i] = adj_src[e + i];
        float2 v[8];
#pragma unroll
        for (int i = 0; i < 8; ++i) v[i] = H2[(size_t)s[i] * 64 + lane];
#pragma unroll
        for (int i = 0; i < 8; ++i) { acc.x += v[i].x; acc.y += v[i].y; }
    }
    for (; e + 2 <= e1; e += 2) {
        int s0 = adj_src[e], s1 = adj_src[e + 1];
        float2 v0 = H2[(size_t)s0 * 64 + lane];
        float2 v1 = H2[(size_t)s1 * 64 + lane];
        acc.x += v0.x + v1.x; acc.y += v0.y + v1.y;
    }
    if (e < e1) {
        float2 v = H2[(size_t)adj_src[e] * 64 + lane];
        acc.x += v.x; acc.y += v.y;
    }

    float di = dinv[node];
    float2 b = ((const float2*)bias)[lane];
    acc.x = fmaxf(fmaf(acc.x, di, b.x), 0.f);
    acc.y = fmaxf(fmaf(acc.y, di, b.y), 0.f);
    ((float2*)out)[(size_t)node * 64 + lane] = acc;
}

// ---------------- launch ----------------

extern "C" void kernel_launch(void* const* d_in, const int* in_sizes, int n_in,
                              void* d_out, int out_size, void* d_ws, size_t ws_size,
                              hipStream_t stream) {
    const float* x  = (const float*)d_in[0];
    const int*   ei = (const int*)d_in[1];
    const float* W1 = (const float*)d_in[2];
    const float* b1 = (const float*)d_in[3];
    const float* W2 = (const float*)d_in[4];
    const float* b2 = (const float*)d_in[5];
    float* out = (float*)d_out;

    const int N = in_sizes[0] / 128;
    const int E = in_sizes[1] / 2;
    const int* src = ei;
    const int* dst = ei + E;

    char* ws = (char*)d_ws;
    size_t off = 0;
    auto alloc = [&](size_t bytes) -> void* {
        void* p = ws + off;
        off = (off + bytes + 255) & ~(size_t)255;
        return p;
    };
    int*   counts  = (int*)  alloc((size_t)N * 4);
    int*   offs    = (int*)  alloc((size_t)(N + 1) * 4);
    int*   cursor  = (int*)  alloc((size_t)N * 4);
    float* dinv    = (float*)alloc((size_t)N * 4);
    int*   adj_src = (int*)  alloc((size_t)E * 4);
    float* h       = (float*)alloc((size_t)N * 128 * 4);
    float* t       = (float*)alloc((size_t)N * 128 * 4);
    int*   blockSums = (int*)alloc((size_t)1024 * 4);
    (void)ws_size; (void)n_in; (void)out_size;

    int gE = (E + 255) / 256;
    int gN = (N + 255) / 256;
    int gG = (N + 31) / 32;
    int gA = (N + 3) / 4;
    int nb = (N + 1023) / 1024;

    hipMemsetAsync(counts, 0, (size_t)N * 4, stream);
    count_k<<<gE, 256, 0, stream>>>(dst, counts, E);
    dinv_k<<<gN, 256, 0, stream>>>(counts, dinv, N);
    scanA_k<<<nb, 256, 0, stream>>>(counts, blockSums, N);
    scanB_k<<<1, 256, 0, stream>>>(blockSums, nb, offs, N);
    scanC_k<<<nb, 256, 0, stream>>>(counts, blockSums, offs, cursor, N);
    fill_k<<<gE, 256, 0, stream>>>(src, dst, cursor, adj_src, E);

    gemm128s<<<gG, 256, 0, stream>>>(x, W1, dinv, h, N);
    agg_k<<<gA, 256, 0, stream>>>(h, offs, adj_src, dinv, b1, t, N);
    gemm128s<<<gG, 256, 0, stream>>>(t, W2, dinv, h, N);
    agg_k<<<gA, 256, 0, stream>>>(h, offs, adj_src, dinv, b2, out, N);
}

// Round 4
// 213.118 us; speedup vs baseline: 1.7172x; 1.1338x over previous
//
#include <hip/hip_runtime.h>
#include <hip/hip_bf16.h>

// GCN 2-layer: h = relu(Agg(x@W1)+b1); out = relu(Agg(h@W2)+b2)
// R1: two-level parallel scan.
// R2: agg unrolled x8; norm folded into gemm epilogue (h2 = (X@W)*dinv[row]).
// R3: GEMM moved to matrix pipe via bf16x3 split (x_hi*W_hi + x_lo*W_hi + x_hi*W_lo),
//     mfma_f32_16x16x32_bf16. W pre-split/transposed to B-frag-linear order once;
//     x split hi/lo during LDS staging with XOR swizzle (G4) for conflict-free
//     A-frag ds_read_b128.

typedef short s16x8 __attribute__((ext_vector_type(8)));
typedef float f32x4 __attribute__((ext_vector_type(4)));

// ---------------- setup kernels ----------------

__global__ void count_k(const int* __restrict__ dst, int* __restrict__ counts, int E) {
    int e = blockIdx.x * 256 + threadIdx.x;
    if (e < E) atomicAdd(&counts[dst[e]], 1);
}

__global__ void dinv_k(const int* __restrict__ counts, float* __restrict__ dinv, int n) {
    int i = blockIdx.x * 256 + threadIdx.x;
    if (i < n) {
        float deg = (float)(counts[i] + 1);   // +1 self-loop
        dinv[i] = rsqrtf(deg);
    }
}

__global__ __launch_bounds__(256) void scanA_k(const int* __restrict__ counts,
                                               int* __restrict__ blockSums, int n) {
    __shared__ int sh[256];
    int base = blockIdx.x * 1024;
    int tid = threadIdx.x;
    int s = 0;
#pragma unroll
    for (int u = 0; u < 4; ++u) {
        int i = base + u * 256 + tid;
        if (i < n) s += counts[i];
    }
    sh[tid] = s;
    __syncthreads();
    for (int off = 128; off > 0; off >>= 1) {
        if (tid < off) sh[tid] += sh[tid + off];
        __syncthreads();
    }
    if (tid == 0) blockSums[blockIdx.x] = sh[0];
}

__global__ __launch_bounds__(256) void scanB_k(int* __restrict__ blockSums, int nb,
                                               int* __restrict__ offs, int n) {
    __shared__ int sh[1024];
    int tid = threadIdx.x;
    for (int i = tid; i < nb; i += 256) sh[i] = blockSums[i];
    __syncthreads();
    if (tid == 0) {
        int run = 0;
        for (int i = 0; i < nb; ++i) { int v = sh[i]; sh[i] = run; run += v; }
        offs[n] = run;
    }
    __syncthreads();
    for (int i = tid; i < nb; i += 256) blockSums[i] = sh[i];
}

__global__ __launch_bounds__(256) void scanC_k(const int* __restrict__ counts,
                                               const int* __restrict__ blockSums,
                                               int* __restrict__ offs,
                                               int* __restrict__ cursor, int n) {
    __shared__ int sh[256];
    int base = blockIdx.x * 1024;
    int tid = threadIdx.x;
    int v[4];
    int s = 0;
#pragma unroll
    for (int u = 0; u < 4; ++u) {
        int i = base + tid * 4 + u;
        v[u] = (i < n) ? counts[i] : 0;
        s += v[u];
    }
    sh[tid] = s;
    __syncthreads();
    for (int off = 1; off < 256; off <<= 1) {
        int t = (tid >= off) ? sh[tid - off] : 0;
        __syncthreads();
        sh[tid] += t;
        __syncthreads();
    }
    int excl = blockSums[blockIdx.x] + sh[tid] - s;
#pragma unroll
    for (int u = 0; u < 4; ++u) {
        int i = base + tid * 4 + u;
        if (i < n) { offs[i] = excl; cursor[i] = excl; }
        excl += v[u];
    }
}

__global__ void fill_k(const int* __restrict__ src, const int* __restrict__ dst,
                       int* __restrict__ cursor, int* __restrict__ adj_src, int E) {
    int e = blockIdx.x * 256 + threadIdx.x;
    if (e < E) {
        int d = dst[e];
        int p = atomicAdd(&cursor[d], 1);
        adj_src[p] = src[e];
    }
}

// ---- W prep: split f32 W[128][128] into bf16 hi/lo, B-frag-linear order ----
// B-frag (16x16x32 mfma): lane l holds B[k][n], k=kt*32+(l>>4)*8+j, n=nt*16+(l&15).
// dest element index = ((kt*8+nt)*64 + l)*8 + j.

__global__ void wprep_k(const float* __restrict__ W,
                        short* __restrict__ wh, short* __restrict__ wl) {
    int tid = blockIdx.x * 256 + threadIdx.x;   // 16384
    int k = tid >> 7, nn = tid & 127;
    float w = W[tid];
    unsigned u = __float_as_uint(w);
    unsigned hibits = (u + 0x7fffu + ((u >> 16) & 1u)) & 0xffff0000u;  // rne bf16
    float whf = __uint_as_float(hibits);
    float rem = w - whf;
    unsigned u2 = __float_as_uint(rem);
    unsigned lobits = (u2 + 0x7fffu + ((u2 >> 16) & 1u)) >> 16;
    int kt = k >> 5, kr = k & 31, nt = nn >> 4, nr = nn & 15;
    int l = ((kr >> 3) << 4) | nr;
    int j = kr & 7;
    int dest = ((kt * 8 + nt) * 64 + l) * 8 + j;
    wh[dest] = (short)(hibits >> 16);
    wl[dest] = (short)lobits;
}

// ---------------- MFMA GEMM: H[n][128] = (X[n][128] @ W[128][128]) * dinv[row] ----
// 64 rows/block, 256 threads (4 waves), wave w owns rows w*16..w*16+15.
// x staged in LDS as bf16 hi/lo with byte-XOR swizzle ((row&7)<<4).

__global__ __launch_bounds__(256) void gemm_mfma(const float* __restrict__ X,
                                                 const short* __restrict__ wbh,
                                                 const short* __restrict__ wbl,
                                                 const float* __restrict__ dinv,
                                                 float* __restrict__ H, int n) {
    __shared__ char lds[32768];            // xh [64][256B] at 0, xl at 16384
    int base = blockIdx.x * 64;
    int tid = threadIdx.x;

    // ---- stage: read f32 x rows, split hi/lo bf16, swizzled ds_write ----
#pragma unroll
    for (int u = 0; u < 4; ++u) {
        int idx = u * 256 + tid;           // 1024 chunks of 8 elements
        int r = idx >> 4;
        int c0 = (idx & 15) * 8;
        int row = base + r;
        float v[8];
        if (row < n) {
            const float4* p = (const float4*)(X + (size_t)row * 128 + c0);
            float4 a = p[0], b = p[1];
            v[0]=a.x; v[1]=a.y; v[2]=a.z; v[3]=a.w;
            v[4]=b.x; v[5]=b.y; v[6]=b.z; v[7]=b.w;
        } else {
#pragma unroll
            for (int i = 0; i < 8; ++i) v[i] = 0.f;
        }
        short hi8[8], lo8[8];
#pragma unroll
        for (int i = 0; i < 8; ++i) {
            unsigned uu = __float_as_uint(v[i]);
            unsigned hb = (uu + 0x7fffu + ((uu >> 16) & 1u)) & 0xffff0000u;
            float rem = v[i] - __uint_as_float(hb);
            unsigned u2 = __float_as_uint(rem);
            unsigned lb = (u2 + 0x7fffu + ((u2 >> 16) & 1u)) >> 16;
            hi8[i] = (short)(hb >> 16);
            lo8[i] = (short)lb;
        }
        int boff = r * 256 + ((c0 * 2) ^ ((r & 7) << 4));
        *(s16x8*)(lds + boff)         = *(const s16x8*)hi8;
        *(s16x8*)(lds + 16384 + boff) = *(const s16x8*)lo8;
    }
    __syncthreads();

    // ---- MFMA main: wave computes 16x128 ----
    int w = tid >> 6;
    int l = tid & 63;
    int rl = l & 15;                       // A row within wave tile
    int kg = l >> 4;                       // k-group
    int row_local = (w << 4) | rl;
    int arow_byte = row_local * 256;
    int aswz = (row_local & 7) << 4;

    const s16x8* bh8 = (const s16x8*)wbh;
    const s16x8* bl8 = (const s16x8*)wbl;

    f32x4 acc[8];
#pragma unroll
    for (int nt = 0; nt < 8; ++nt) acc[nt] = (f32x4){0.f, 0.f, 0.f, 0.f};

#pragma unroll
    for (int kt = 0; kt < 4; ++kt) {
        int coff = (kt * 64 + (kg << 4)) ^ aswz;
        s16x8 ah = *(const s16x8*)(lds + arow_byte + coff);
        s16x8 al = *(const s16x8*)(lds + 16384 + arow_byte + coff);
#pragma unroll
        for (int nt = 0; nt < 8; ++nt) {
            s16x8 bh = bh8[(kt * 8 + nt) * 64 + l];
            s16x8 bl = bl8[(kt * 8 + nt) * 64 + l];
            acc[nt] = __builtin_amdgcn_mfma_f32_16x16x32_bf16(ah, bh, acc[nt], 0, 0, 0);
            acc[nt] = __builtin_amdgcn_mfma_f32_16x16x32_bf16(al, bh, acc[nt], 0, 0, 0);
            acc[nt] = __builtin_amdgcn_mfma_f32_16x16x32_bf16(ah, bl, acc[nt], 0, 0, 0);
        }
    }

    // ---- epilogue: C/D layout col=lane&15, row=(lane>>4)*4+reg ----
    int r0 = base + (w << 4) + (kg << 2);
    float d0 = (r0 + 0 < n) ? dinv[r0 + 0] : 0.f;
    float d1 = (r0 + 1 < n) ? dinv[r0 + 1] : 0.f;
    float d2 = (r0 + 2 < n) ? dinv[r0 + 2] : 0.f;
    float d3 = (r0 + 3 < n) ? dinv[r0 + 3] : 0.f;
#pragma unroll
    for (int nt = 0; nt < 8; ++nt) {
        int col = (nt << 4) | rl;
        if (r0 + 0 < n) H[(size_t)(r0 + 0) * 128 + col] = acc[nt][0] * d0;
        if (r0 + 1 < n) H[(size_t)(r0 + 1) * 128 + col] = acc[nt][1] * d1;
        if (r0 + 2 < n) H[(size_t)(r0 + 2) * 128 + col] = acc[nt][2] * d2;
        if (r0 + 3 < n) H[(size_t)(r0 + 3) * 128 + col] = acc[nt][3] * d3;
    }
}

// ---------------- aggregation ----------------
// H2 is pre-scaled by dinv[src]. out[d] = relu(dinv[d]*(sum h2[s] + h2[d]) + b)

__global__ __launch_bounds__(256) void agg_k(const float* __restrict__ Hs,
                                             const int* __restrict__ offs,
                                             const int* __restrict__ adj_src,
                                             const float* __restrict__ dinv,
                                             const float* __restrict__ bias,
                                             float* __restrict__ out, int n) {
    int node = blockIdx.x * 4 + (threadIdx.x >> 6);
    if (node >= n) return;
    int lane = threadIdx.x & 63;

    const float2* H2 = (const float2*)Hs;
    float2 acc = H2[(size_t)node * 64 + lane];     // self term (pre-scaled)

    int e = offs[node];
    int e1 = offs[node + 1];

    for (; e + 8 <= e1; e += 8) {
        int s[8];
#pragma unroll
        for (int i = 0; i < 8; ++i) s[i] = adj_src[e + i];
        float2 v[8];
#pragma unroll
        for (int i = 0; i < 8; ++i) v[i] = H2[(size_t)s[i] * 64 + lane];
#pragma unroll
        for (int i = 0; i < 8; ++i) { acc.x += v[i].x; acc.y += v[i].y; }
    }
    for (; e + 2 <= e1; e += 2) {
        int s0 = adj_src[e], s1 = adj_src[e + 1];
        float2 v0 = H2[(size_t)s0 * 64 + lane];
        float2 v1 = H2[(size_t)s1 * 64 + lane];
        acc.x += v0.x + v1.x; acc.y += v0.y + v1.y;
    }
    if (e < e1) {
        float2 v = H2[(size_t)adj_src[e] * 64 + lane];
        acc.x += v.x; acc.y += v.y;
    }

    float di = dinv[node];
    float2 b = ((const float2*)bias)[lane];
    acc.x = fmaxf(fmaf(acc.x, di, b.x), 0.f);
    acc.y = fmaxf(fmaf(acc.y, di, b.y), 0.f);
    ((float2*)out)[(size_t)node * 64 + lane] = acc;
}

// ---------------- launch ----------------

extern "C" void kernel_launch(void* const* d_in, const int* in_sizes, int n_in,
                              void* d_out, int out_size, void* d_ws, size_t ws_size,
                              hipStream_t stream) {
    const float* x  = (const float*)d_in[0];
    const int*   ei = (const int*)d_in[1];
    const float* W1 = (const float*)d_in[2];
    const float* b1 = (const float*)d_in[3];
    const float* W2 = (const float*)d_in[4];
    const float* b2 = (const float*)d_in[5];
    float* out = (float*)d_out;

    const int N = in_sizes[0] / 128;
    const int E = in_sizes[1] / 2;
    const int* src = ei;
    const int* dst = ei + E;

    char* ws = (char*)d_ws;
    size_t off = 0;
    auto alloc = [&](size_t bytes) -> void* {
        void* p = ws + off;
        off = (off + bytes + 255) & ~(size_t)255;
        return p;
    };
    int*   counts  = (int*)  alloc((size_t)N * 4);
    int*   offs    = (int*)  alloc((size_t)(N + 1) * 4);
    int*   cursor  = (int*)  alloc((size_t)N * 4);
    float* dinv    = (float*)alloc((size_t)N * 4);
    int*   adj_src = (int*)  alloc((size_t)E * 4);
    float* h       = (float*)alloc((size_t)N * 128 * 4);
    float* t       = (float*)alloc((size_t)N * 128 * 4);
    int*   blockSums = (int*)alloc((size_t)1024 * 4);
    short* w1h = (short*)alloc((size_t)128 * 128 * 2);
    short* w1l = (short*)alloc((size_t)128 * 128 * 2);
    short* w2h = (short*)alloc((size_t)128 * 128 * 2);
    short* w2l = (short*)alloc((size_t)128 * 128 * 2);
    (void)ws_size; (void)n_in; (void)out_size;

    int gE = (E + 255) / 256;
    int gN = (N + 255) / 256;
    int gG = (N + 63) / 64;
    int gA = (N + 3) / 4;
    int nb = (N + 1023) / 1024;

    hipMemsetAsync(counts, 0, (size_t)N * 4, stream);
    wprep_k<<<64, 256, 0, stream>>>(W1, w1h, w1l);
    wprep_k<<<64, 256, 0, stream>>>(W2, w2h, w2l);
    count_k<<<gE, 256, 0, stream>>>(dst, counts, E);
    dinv_k<<<gN, 256, 0, stream>>>(counts, dinv, N);
    scanA_k<<<nb, 256, 0, stream>>>(counts, blockSums, N);
    scanB_k<<<1, 256, 0, stream>>>(blockSums, nb, offs, N);
    scanC_k<<<nb, 256, 0, stream>>>(counts, blockSums, offs, cursor, N);
    fill_k<<<gE, 256, 0, stream>>>(src, dst, cursor, adj_src, E);

    gemm_mfma<<<gG, 256, 0, stream>>>(x, w1h, w1l, dinv, h, N);
    agg_k<<<gA, 256, 0, stream>>>(h, offs, adj_src, dinv, b1, t, N);
    gemm_mfma<<<gG, 256, 0, stream>>>(t, w2h, w2l, dinv, h, N);
    agg_k<<<gA, 256, 0, stream>>>(h, offs, adj_src, dinv, b2, out, N);
}